// Round 10
// baseline (170.229 us; speedup 1.0000x reference)
//
#include <hip/hip_runtime.h>
#include <math.h>

#define BB 4
#define NLL 2048
#define CC 128
#define HH 128
#define WW 128
#define NPTS0 32
#define NPTS1 8
#define PP 64
#define FDIM 5
#define FCK (CC*NPTS1 + FDIM)   // 1029
#define FCKP 1032               // padded stride for aligned float4 loads

typedef __attribute__((ext_vector_type(8))) short bf16x8;
typedef __attribute__((ext_vector_type(4))) float f32x4;
typedef __attribute__((ext_vector_type(2))) float f32x2;
typedef __attribute__((ext_vector_type(4))) unsigned u32x4;

__device__ __forceinline__ unsigned short f2bf(float f) {
    union { float f; unsigned u; } v; v.f = f;
    unsigned u = v.u;
    return (unsigned short)((u + 0x7fffu + ((u >> 16) & 1u)) >> 16);
}
__device__ __forceinline__ float bf2f(unsigned short s) {
    union { unsigned u; float f; } v; v.u = ((unsigned)s) << 16;
    return v.f;
}
__device__ __forceinline__ unsigned cvt_pk_bf16(float a, float b) {
    unsigned r;
    asm("v_cvt_pk_bf16_f32 %0, %1, %2" : "=v"(r) : "v"(a), "v"(b));
    return r;
}
__device__ __forceinline__ f32x2 pk_mul(f32x2 a, f32x2 b) {
    f32x2 d;
    asm("v_pk_mul_f32 %0, %1, %2" : "=v"(d) : "v"(a), "v"(b));
    return d;
}
__device__ __forceinline__ f32x2 pk_fma(f32x2 a, f32x2 b, f32x2 c) {
    f32x2 d;
    asm("v_pk_fma_f32 %0, %1, %2, %3" : "=v"(d) : "v"(a), "v"(b), "v"(c));
    return d;
}
__device__ __forceinline__ f32x2 bfpair(unsigned u) {
    union { unsigned v; float f; } lo, hi;
    lo.v = u << 16;
    hi.v = u & 0xffff0000u;
    f32x2 r; r.x = lo.f; r.y = hi.f;
    return r;
}
// Raw barrier with LDS-only drain: __syncthreads() emits a full
// s_waitcnt vmcnt(0) lgkmcnt(0) which kills in-flight global prefetches.
// All inter-phase communication in line_mfma is through LDS, so
// lgkmcnt(0)+s_barrier is sufficient ordering; weight loads issued at
// kernel top stay in flight across phase boundaries.
__device__ __forceinline__ void bar_lds() {
    asm volatile("s_waitcnt lgkmcnt(0)" ::: "memory");
    __builtin_amdgcn_s_barrier();
}

// ---------------------------------------------------------------------------
// Transpose v7 (unchanged): 2048 tile blocks + cvt_pk conversion.
// Blocks [2048,2064): weight prep.
// ---------------------------------------------------------------------------
__global__ __launch_bounds__(256)
void transpose_prep(const float* __restrict__ fm, const float* __restrict__ w1,
                    const float* __restrict__ w2, const float* __restrict__ w3,
                    const float* __restrict__ fcw,
                    unsigned short* __restrict__ fmT,
                    unsigned short* __restrict__ W1b,
                    unsigned short* __restrict__ W2b,
                    unsigned short* __restrict__ W3b,
                    float* __restrict__ fcwP) {
    const int t = threadIdx.x;
    if (blockIdx.x >= 2048) {
        int gid = (blockIdx.x - 2048) * 256 + t;
        for (int e = gid; e < 32800; e += 4096) {
            if (e < 8192) {
                W1b[e] = f2bf(w1[e]);
            } else if (e < 20480) {
                int g = e - 8192;
                int tt = g >> 12, r = g & 4095;
                int p = r >> 6, q = r & 63;
                W2b[tt * 4096 + p * 64 + q] = f2bf(w2[p * 192 + q * 3 + tt]);
            } else if (e < 28672) {
                int g = e - 20480;
                W3b[g] = f2bf(w3[g]);
            } else {
                int g = e - 28672;              // 0..4127
                int o = g / FCKP, r = g - o * FCKP;
                fcwP[g] = (r < FCK) ? fcw[o * FCK + r] : 0.0f;
            }
        }
        return;
    }
    __shared__ unsigned short tile[64 * 72];    // 9 KiB
    const int bh = blockIdx.x;
    const int by = bh >> 2;               // b*H + y
    const int xh = (bh >> 1) & 1;         // x half
    const int ch = bh & 1;                // channel half
    const int b = by >> 7, y = by & 127;
    const float* src = fm + ((size_t)b * CC + ch * 64) * (HH * WW)
                     + (size_t)y * WW + xh * 64;
    const int x4 = (t & 15) * 4;          // 0..60 within the x half
    #pragma unroll
    for (int i = 0; i < 4; ++i) {
        int r = (t >> 4) + 16 * i;        // channel within group, 0..63
        float4 v = *(const float4*)&src[(size_t)r * (HH * WW) + x4];
        uint2 u;
        u.x = cvt_pk_bf16(v.x, v.y);
        u.y = cvt_pk_bf16(v.z, v.w);
        *(uint2*)&tile[r * 72 + (x4 ^ (r & 28))] = u;
    }
    __syncthreads();
    const int c4 = (t & 15) * 4;          // channel (within group) 0..60
    unsigned short* dst = fmT + ((size_t)by * WW + xh * 64) * CC + ch * 64;
    #pragma unroll
    for (int i = 0; i < 4; ++i) {
        int x = (t >> 4) + 16 * i;        // 0..63
        ushort4 u;
        u.x = tile[(c4 + 0) * 72 + (x ^ ((c4 + 0) & 28))];
        u.y = tile[(c4 + 1) * 72 + (x ^ ((c4 + 1) & 28))];
        u.z = tile[(c4 + 2) * 72 + (x ^ ((c4 + 2) & 28))];
        u.w = tile[(c4 + 3) * 72 + (x ^ ((c4 + 3) & 28))];
        *(ushort4*)&dst[(size_t)x * CC + c4] = u;
    }
}

// ---------------------------------------------------------------------------
// Fused line pipeline v12 (resubmission -- R9 bench was an infra failure,
// "container failed twice", no kernel verdict). v12 = v10 (proven 48.5us)
// + two surgical changes:
//  (1) all 5 barriers are bar_lds (s_barrier + lgkmcnt only, NO vmcnt drain)
//  (2) ALL conv-phase weights/params issued once at kernel top, fenced by
//      sched_barrier(0) (no "+v" pins -- R5 showed pins force a vmcnt wait
//      at the pin site). They drain under P0+P1 and survive barriers.
// Tripwires: VGPR ~100-110 proves payload lives; WRITE_SIZE must stay
// ~0.26MB (no spill); absmax <= 0.0625.
// MFMA 16x16x32 bf16 mapping: A[m=lane&15][k=quad*8+j], C/D col=lane&15,
// row=quad*4+reg.
// ---------------------------------------------------------------------------
__global__ __launch_bounds__(256, 4)
void line_mfma(const unsigned short* __restrict__ fmT,   // (B,H,W,C) bf16
               const float* __restrict__ lines,
               const float* __restrict__ bn1_g, const float* __restrict__ bn1_b,
               const unsigned short* __restrict__ W1b, const float* __restrict__ b1,
               const float* __restrict__ bn2_g, const float* __restrict__ bn2_b,
               const unsigned short* __restrict__ W2b, const float* __restrict__ b2,
               const float* __restrict__ bn3_g, const float* __restrict__ bn3_b,
               const unsigned short* __restrict__ W3b, const float* __restrict__ b3,
               const float* __restrict__ fcwP,  const float* __restrict__ fcb,
               float* __restrict__ out) {
    __shared__ int   s_oA[64], s_oB[64], s_oC[64], s_oD[64];   // element offsets
    __shared__ float s_wA[64], s_wB[64], s_wC[64], s_wD[64];
    __shared__ float s_xs[16 * 132];             // residual, fp32, [m][c] pad 4
    __shared__ unsigned short s_ybn[16 * 136];   // relu(bn1), bf16, [m][c]
    __shared__ unsigned short s_z1[2 * 10 * 72]; // conv1 out, halo rows 0/9 zero
    __shared__ unsigned short s_z2[16 * 72];     // conv2 out, [m][q]
    __shared__ float s_feat[2][8];
    __shared__ float s_red[4 * 8];

    const int bx  = blockIdx.x;
    const int wg  = (bx & 7) * 512 + (bx >> 3);  // XCD swizzle: 1 batch per 2 XCDs
    const int L0  = wg * 2;
    const int b   = wg >> 10;
    const int tid = threadIdx.x;
    const int lane = tid & 63;
    const int wv   = tid >> 6;
    const int quad = lane >> 4;
    const int l16  = lane & 15;
    const float inv_s = 1.0f / sqrtf(1.0f + 1e-5f);

    // ---- Top-of-kernel weight/param prefetch (issued before P0; drains
    //      under P0+P1; survives barriers because bar_lds doesn't drain
    //      vmcnt). sched_barrier(0) pins issue order without forcing waits.
    const int pP  = wv * 16 + l16;          // conv1/conv2 output channel
    const int cA  = wv * 32 + l16;          // conv3 sub0 output channel
    const int cB  = wv * 32 + 16 + l16;     // conv3 sub1 output channel
    bf16x8 w1p[4], w2p[3][2], w3p0[2], w3p1[2];
    {
        const unsigned short* wr1 = W1b + pP * 128 + quad * 8;
        w1p[0] = *(const bf16x8*)(wr1 + 0 * 32);
        w1p[1] = *(const bf16x8*)(wr1 + 1 * 32);
        w1p[2] = *(const bf16x8*)(wr1 + 2 * 32);
        w1p[3] = *(const bf16x8*)(wr1 + 3 * 32);
        #pragma unroll
        for (int t = 0; t < 3; ++t) {
            const unsigned short* wr2 = W2b + t * 4096 + pP * 64 + quad * 8;
            w2p[t][0] = *(const bf16x8*)(wr2 + 0 * 32);
            w2p[t][1] = *(const bf16x8*)(wr2 + 1 * 32);
        }
        const unsigned short* wr3a = W3b + cA * 64 + quad * 8;
        const unsigned short* wr3b = W3b + cB * 64 + quad * 8;
        w3p0[0] = *(const bf16x8*)(wr3a + 0 * 32);
        w3p0[1] = *(const bf16x8*)(wr3a + 1 * 32);
        w3p1[0] = *(const bf16x8*)(wr3b + 0 * 32);
        w3p1[1] = *(const bf16x8*)(wr3b + 1 * 32);
    }
    float pf_s2  = bn2_g[pP], pf_bb2 = bn2_b[pP], pf_cb1 = b1[pP];
    float pf_s3  = bn3_g[pP], pf_bb3 = bn3_b[pP], pf_cb2 = b2[pP];
    float pf_cb3a = b3[cA],   pf_cb3b = b3[cB];
    __builtin_amdgcn_sched_barrier(0);   // keep all prefetch issues HERE

    // ---- P0: per-point offsets/weights, line features, halo zeroing ----
    if (tid < 64) {
        int line = tid >> 5, pt = tid & 31;
        const float* ln = lines + (size_t)(L0 + line) * 4;
        float lam = (float)pt * (1.0f / 31.0f);
        float om  = 1.0f - lam;
        float px = ln[0] * lam + ln[2] * om - 0.5f;
        float py = ln[1] * lam + ln[3] * om - 0.5f;
        float px0 = fminf(fmaxf(floorf(px), 0.0f), 127.0f);
        float py0 = fminf(fmaxf(floorf(py), 0.0f), 127.0f);
        float px1 = fminf(px0 + 1.0f, 127.0f);
        float py1 = fminf(py0 + 1.0f, 127.0f);
        int ix0 = (int)px0, ix1 = (int)px1, iy0 = (int)py0, iy1 = (int)py1;
        s_oA[tid] = (iy0 * WW + ix0) * CC;
        s_oB[tid] = (iy1 * WW + ix0) * CC;
        s_oC[tid] = (iy0 * WW + ix1) * CC;
        s_oD[tid] = (iy1 * WW + ix1) * CC;
        float ax = px1 - px, bxv = px - px0, ay = py1 - py, byv = py - py0;
        // exact reference pairing (its bilinear weights are x/y-swapped)
        s_wA[tid] = ax  * ay;
        s_wB[tid] = bxv * ay;
        s_wC[tid] = ax  * byv;
        s_wD[tid] = bxv * byv;
    }
    if (tid >= 64 && tid < 66) {
        int line = tid - 64;
        const float* ln = lines + (size_t)(L0 + line) * 4;
        float ux = ln[0], uy = ln[1], vx = ln[2], vy = ln[3];
        float dx = ux - vx, dy = uy - vy;
        float d = fmaxf(sqrtf(dx * dx + dy * dy), 1e-6f);
        s_feat[line][0] = ux * (1.0f / 128.0f);
        s_feat[line][1] = uy * (1.0f / 128.0f);
        s_feat[line][2] = vx * (1.0f / 128.0f);
        s_feat[line][3] = vy * (1.0f / 128.0f);
        s_feat[line][4] = d;
    }
    if (tid < 128) {
        int line = tid >> 6, q = tid & 63;
        s_z1[line * 720 + 0 * 72 + q] = 0;
        s_z1[line * 720 + 9 * 72 + q] = 0;
    }
    bar_lds();

    // ---- P1: bf16 gather + packed bilinear + maxpool(4) -> s_xs (fp32)
    //          + fused bn1+relu+cvt_pk -> s_ybn ----
    {
        int tl = tid >> 4;               // m = line*8 + k, 0..15
        int c8 = (tid & 15) * 8;
        const unsigned short* base = fmT + (size_t)b * (HH * WW * CC) + c8;
        const int pt0 = (tl >> 3) * 32 + (tl & 7) * 4;
        u32x4 rA[4], rB[4], rC[4], rD[4];
        #pragma unroll
        for (int j = 0; j < 4; ++j) {
            rA[j] = *(const u32x4*)(base + s_oA[pt0 + j]);
            rB[j] = *(const u32x4*)(base + s_oB[pt0 + j]);
            rC[j] = *(const u32x4*)(base + s_oC[pt0 + j]);
            rD[j] = *(const u32x4*)(base + s_oD[pt0 + j]);
        }
        float acc[8];
        #pragma unroll
        for (int i = 0; i < 8; ++i) acc[i] = -INFINITY;
        #pragma unroll
        for (int j = 0; j < 4; ++j) {
            int pt = pt0 + j;
            float wA = s_wA[pt], wB = s_wB[pt], wC = s_wC[pt], wD = s_wD[pt];
            f32x2 wA2 = {wA, wA}, wB2 = {wB, wB};
            f32x2 wC2 = {wC, wC}, wD2 = {wD, wD};
            #pragma unroll
            for (int p2 = 0; p2 < 4; ++p2) {
                f32x2 t = pk_mul(wA2, bfpair(rA[j][p2]));
                t = pk_fma(wB2, bfpair(rB[j][p2]), t);
                t = pk_fma(wC2, bfpair(rC[j][p2]), t);
                t = pk_fma(wD2, bfpair(rD[j][p2]), t);
                acc[2 * p2]     = fmaxf(acc[2 * p2],     t.x);
                acc[2 * p2 + 1] = fmaxf(acc[2 * p2 + 1], t.y);
            }
        }
        float* xr = &s_xs[tl * 132 + c8];
        f32x4 lo = {acc[0], acc[1], acc[2], acc[3]};
        f32x4 hi = {acc[4], acc[5], acc[6], acc[7]};
        *(f32x4*)&xr[0] = lo;
        *(f32x4*)&xr[4] = hi;
        // fused bn1 + relu + packed cvt (vectorized param loads)
        float4 g0 = *(const float4*)(bn1_g + c8);
        float4 g1 = *(const float4*)(bn1_g + c8 + 4);
        float4 v0 = *(const float4*)(bn1_b + c8);
        float4 v1 = *(const float4*)(bn1_b + c8 + 4);
        float y0 = fmaxf(acc[0] * (g0.x * inv_s) + v0.x, 0.0f);
        float y1 = fmaxf(acc[1] * (g0.y * inv_s) + v0.y, 0.0f);
        float y2 = fmaxf(acc[2] * (g0.z * inv_s) + v0.z, 0.0f);
        float y3 = fmaxf(acc[3] * (g0.w * inv_s) + v0.w, 0.0f);
        float y4 = fmaxf(acc[4] * (g1.x * inv_s) + v1.x, 0.0f);
        float y5 = fmaxf(acc[5] * (g1.y * inv_s) + v1.y, 0.0f);
        float y6 = fmaxf(acc[6] * (g1.z * inv_s) + v1.z, 0.0f);
        float y7 = fmaxf(acc[7] * (g1.w * inv_s) + v1.w, 0.0f);
        u32x4 pk;
        pk[0] = cvt_pk_bf16(y0, y1);
        pk[1] = cvt_pk_bf16(y2, y3);
        pk[2] = cvt_pk_bf16(y4, y5);
        pk[3] = cvt_pk_bf16(y6, y7);
        *(u32x4*)&s_ybn[tl * 136 + c8] = pk;
    }
    bar_lds();

    // ---- P2: conv1 (M=16,K=128,N=64) + bn2 + relu -> s_z1 ----
    // Weights come from the top-of-kernel prefetch (w1p) -- long retired.
    {
        f32x4 acc = {0.f, 0.f, 0.f, 0.f};
        #pragma unroll
        for (int kc = 0; kc < 4; ++kc) {
            bf16x8 a = *(const bf16x8*)&s_ybn[l16 * 136 + kc * 32 + quad * 8];
            acc = __builtin_amdgcn_mfma_f32_16x16x32_bf16(a, w1p[kc], acc, 0, 0, 0);
        }
        float s2 = pf_s2 * inv_s, bb2 = pf_bb2, cb = pf_cb1;
        int line = quad >> 1;
        int kbase = (quad & 1) * 4;
        float v0 = fmaxf((acc[0] + cb) * s2 + bb2, 0.0f);
        float v1 = fmaxf((acc[1] + cb) * s2 + bb2, 0.0f);
        float v2 = fmaxf((acc[2] + cb) * s2 + bb2, 0.0f);
        float v3 = fmaxf((acc[3] + cb) * s2 + bb2, 0.0f);
        unsigned pk01 = cvt_pk_bf16(v0, v1);
        unsigned pk23 = cvt_pk_bf16(v2, v3);
        unsigned short* zr = &s_z1[line * 720 + (kbase + 1) * 72 + pP];
        zr[0 * 72] = (unsigned short)pk01;
        zr[1 * 72] = (unsigned short)(pk01 >> 16);
        zr[2 * 72] = (unsigned short)pk23;
        zr[3 * 72] = (unsigned short)(pk23 >> 16);
    }
    bar_lds();

    // ---- P3: conv2 (3 shifted GEMMs, M=16,K=64,N=64) + bn3 + relu -> s_z2 ----
    {
        f32x4 acc = {0.f, 0.f, 0.f, 0.f};
        int line = l16 >> 3, k = l16 & 7;
        #pragma unroll
        for (int t = 0; t < 3; ++t) {
            const unsigned short* arow = &s_z1[line * 720 + (k + t) * 72];
            #pragma unroll
            for (int kc = 0; kc < 2; ++kc) {
                bf16x8 a = *(const bf16x8*)&arow[kc * 32 + quad * 8];
                acc = __builtin_amdgcn_mfma_f32_16x16x32_bf16(a, w2p[t][kc], acc, 0, 0, 0);
            }
        }
        float s3 = pf_s3 * inv_s, bb3 = pf_bb3, cb = pf_cb2;
        float v0 = fmaxf((acc[0] + cb) * s3 + bb3, 0.0f);
        float v1 = fmaxf((acc[1] + cb) * s3 + bb3, 0.0f);
        float v2 = fmaxf((acc[2] + cb) * s3 + bb3, 0.0f);
        float v3 = fmaxf((acc[3] + cb) * s3 + bb3, 0.0f);
        unsigned pk01 = cvt_pk_bf16(v0, v1);
        unsigned pk23 = cvt_pk_bf16(v2, v3);
        unsigned short* zr = &s_z2[(quad * 4) * 72 + pP];
        zr[0 * 72] = (unsigned short)pk01;
        zr[1 * 72] = (unsigned short)(pk01 >> 16);
        zr[2 * 72] = (unsigned short)pk23;
        zr[3 * 72] = (unsigned short)(pk23 >> 16);
    }
    bar_lds();

    // ---- P4: conv3 (M=16,K=64,N=128) + residual + relu + fc2 partials ----
    f32x2 P0 = {0.f, 0.f}, P1v = {0.f, 0.f}, P2v = {0.f, 0.f}, P3v = {0.f, 0.f};
    {
        int kbase = (quad & 1) * 4;
        bf16x8 a0 = *(const bf16x8*)&s_z2[l16 * 72 + 0 * 32 + quad * 8];
        bf16x8 a1 = *(const bf16x8*)&s_z2[l16 * 72 + 1 * 32 + quad * 8];
        #pragma unroll
        for (int sub = 0; sub < 2; ++sub) {
            f32x4 acc = {0.f, 0.f, 0.f, 0.f};
            acc = __builtin_amdgcn_mfma_f32_16x16x32_bf16(
                a0, sub ? w3p1[0] : w3p0[0], acc, 0, 0, 0);
            acc = __builtin_amdgcn_mfma_f32_16x16x32_bf16(
                a1, sub ? w3p1[1] : w3p0[1], acc, 0, 0, 0);
            int c = sub ? cB : cA;
            float cb = sub ? pf_cb3b : pf_cb3a;
            int idx = c * 8 + kbase;
            float4 w0 = *(const float4*)(fcwP + 0 * FCKP + idx);
            float4 w1w = *(const float4*)(fcwP + 1 * FCKP + idx);
            float4 w2w = *(const float4*)(fcwP + 2 * FCKP + idx);
            float4 w3w = *(const float4*)(fcwP + 3 * FCKP + idx);
            #pragma unroll
            for (int rp = 0; rp < 2; ++rp) {
                int m = quad * 4 + rp * 2;
                float e0 = fmaxf(s_xs[m * 132 + c] + acc[rp * 2] + cb, 0.0f);
                float e1 = fmaxf(s_xs[(m + 1) * 132 + c] + acc[rp * 2 + 1] + cb, 0.0f);
                f32x2 vv = {e0, e1};
                float w0lo = rp ? w0.z : w0.x,  w0hi = rp ? w0.w : w0.y;
                float w1lo = rp ? w1w.z : w1w.x, w1hi = rp ? w1w.w : w1w.y;
                float w2lo = rp ? w2w.z : w2w.x, w2hi = rp ? w2w.w : w2w.y;
                float w3lo = rp ? w3w.z : w3w.x, w3hi = rp ? w3w.w : w3w.y;
                f32x2 w0p = {w0lo, w0hi}, w1p2 = {w1lo, w1hi};
                f32x2 w2p2 = {w2lo, w2hi}, w3p2 = {w3lo, w3hi};
                P0  = pk_fma(vv, w0p, P0);
                P1v = pk_fma(vv, w1p2, P1v);
                P2v = pk_fma(vv, w2p2, P2v);
                P3v = pk_fma(vv, w3p2, P3v);
            }
        }
    }
    float p0 = P0.x + P0.y, p1 = P1v.x + P1v.y;
    float p2 = P2v.x + P2v.y, p3 = P3v.x + P3v.y;
    #pragma unroll
    for (int off = 16; off >= 1; off >>= 1) {
        p0 += __shfl_down(p0, off);
        p1 += __shfl_down(p1, off);
        p2 += __shfl_down(p2, off);
        p3 += __shfl_down(p3, off);
    }
    if ((lane & 31) == 0) {
        int line = lane >> 5;
        s_red[wv * 8 + line * 4 + 0] = p0;
        s_red[wv * 8 + line * 4 + 1] = p1;
        s_red[wv * 8 + line * 4 + 2] = p2;
        s_red[wv * 8 + line * 4 + 3] = p3;
    }
    bar_lds();

    // ---- P5: finish logits + softmax ----
    if (tid < 2) {
        int line = tid;
        float lg[4];
        #pragma unroll
        for (int o = 0; o < 4; ++o) {
            lg[o] = fcb[o] + s_red[0 + line * 4 + o] + s_red[8 + line * 4 + o]
                  + s_red[16 + line * 4 + o] + s_red[24 + line * 4 + o];
        }
        #pragma unroll
        for (int j = 0; j < FDIM; ++j) {
            float fv = fmaxf(s_feat[line][j], 0.0f);
            #pragma unroll
            for (int o = 0; o < 4; ++o)
                lg[o] = fmaf(fv, fcwP[o * FCKP + 1024 + j], lg[o]);
        }
        float m = fmaxf(fmaxf(lg[0], lg[1]), fmaxf(lg[2], lg[3]));
        float e0 = expf(lg[0] - m), e1 = expf(lg[1] - m);
        float e2 = expf(lg[2] - m), e3 = expf(lg[3] - m);
        float inv = 1.0f / (e0 + e1 + e2 + e3);
        float* lo = out + (size_t)(L0 + line) * 4;
        lo[0] = lg[0]; lo[1] = lg[1]; lo[2] = lg[2]; lo[3] = lg[3];
        float* pr = out + (size_t)BB * NLL * 4 + (size_t)(L0 + line) * 4;
        pr[0] = e0 * inv; pr[1] = e1 * inv; pr[2] = e2 * inv; pr[3] = e3 * inv;
    }
}

// ---------------------------------------------------------------------------
// Fallbacks (small-ws paths): round-1 proven VALU kernel + fp32 transpose.
// ---------------------------------------------------------------------------
__global__ __launch_bounds__(256)
void transpose_fm2(const float* __restrict__ fm, float* __restrict__ fmT) {
    __shared__ float tile[32 * 132];
    const int c0 = blockIdx.x * 32;
    const int by = blockIdx.y;
    const int b = by >> 7, y = by & 127;
    const int t = threadIdx.x;
    const float* src = fm + ((size_t)b * CC) * (HH * WW) + (size_t)y * WW;
    const int x4 = (t & 31) * 4;
    #pragma unroll
    for (int i = 0; i < 4; ++i) {
        int r = (t >> 5) + 8 * i;
        *(float4*)&tile[r * 132 + x4] =
            *(const float4*)&src[(size_t)(c0 + r) * (HH * WW) + x4];
    }
    __syncthreads();
    float* dst = fmT + (size_t)by * WW * CC + c0 + (t & 31);
    const int cr = (t & 31) * 132;
    #pragma unroll
    for (int i = 0; i < 16; ++i) {
        int x = (t >> 5) + 8 * i;
        dst[(size_t)x * CC] = tile[cr + x];
    }
}

template<bool TRANS>
__global__ __launch_bounds__(256)
void line_kernel_v1(const float* __restrict__ fm,
                    const float* __restrict__ lines,
                    const float* __restrict__ bn1_g, const float* __restrict__ bn1_b,
                    const float* __restrict__ w1,    const float* __restrict__ b1,
                    const float* __restrict__ bn2_g, const float* __restrict__ bn2_b,
                    const float* __restrict__ w2,    const float* __restrict__ b2,
                    const float* __restrict__ bn3_g, const float* __restrict__ bn3_b,
                    const float* __restrict__ w3,    const float* __restrict__ b3,
                    const float* __restrict__ fcw,   const float* __restrict__ fcb,
                    float* __restrict__ out) {
    __shared__ int   s_ix0[32], s_ix1[32], s_iy0[32], s_iy1[32];
    __shared__ float s_wA[32], s_wB[32], s_wC[32], s_wD[32];
    __shared__ float xs [8][132];
    __shared__ float ybn[8][132];
    __shared__ float z1 [64][12];
    __shared__ float z2 [64][8];
    __shared__ float s_feat[8];
    __shared__ float s_red[16];

    const int L   = blockIdx.x;
    const int b   = L / NLL;
    const int tid = threadIdx.x;
    const float inv_s = 1.0f / sqrtf(1.0f + 1e-5f);
    const float* ln = lines + (size_t)L * 4;

    if (tid < 32) {
        float lam = (float)tid * (1.0f / 31.0f);
        float om  = 1.0f - lam;
        float px = ln[0] * lam + ln[2] * om - 0.5f;
        float py = ln[1] * lam + ln[3] * om - 0.5f;
        float px0 = fminf(fmaxf(floorf(px), 0.0f), 127.0f);
        float py0 = fminf(fmaxf(floorf(py), 0.0f), 127.0f);
        float px1 = fminf(px0 + 1.0f, 127.0f);
        float py1 = fminf(py0 + 1.0f, 127.0f);
        s_ix0[tid] = (int)px0; s_ix1[tid] = (int)px1;
        s_iy0[tid] = (int)py0; s_iy1[tid] = (int)py1;
        float ax = px1 - px, bxv = px - px0, ay = py1 - py, byv = py - py0;
        s_wA[tid] = ax  * ay;  s_wB[tid] = bxv * ay;
        s_wC[tid] = ax  * byv; s_wD[tid] = bxv * byv;
    }
    if (tid == 0) {
        float ux = ln[0], uy = ln[1], vx = ln[2], vy = ln[3];
        float dx = ux - vx, dy = uy - vy;
        float d = fmaxf(sqrtf(dx * dx + dy * dy), 1e-6f);
        s_feat[0] = ux / 128.0f; s_feat[1] = uy / 128.0f;
        s_feat[2] = vx / 128.0f; s_feat[3] = vy / 128.0f;
        s_feat[4] = d;
    }
    __syncthreads();
    {
        int cq = tid & 31, k = tid >> 5, c0 = cq * 4;
        float4 acc;
        acc.x = -INFINITY; acc.y = -INFINITY; acc.z = -INFINITY; acc.w = -INFINITY;
        #pragma unroll
        for (int j = 0; j < 4; ++j) {
            int pt = k * 4 + j;
            int ix0 = s_ix0[pt], ix1 = s_ix1[pt];
            int iy0 = s_iy0[pt], iy1 = s_iy1[pt];
            float wA = s_wA[pt], wB = s_wB[pt], wC = s_wC[pt], wD = s_wD[pt];
            float4 vA, vB, vC, vD;
            if (TRANS) {
                const float* base = fm + (size_t)b * HH * WW * CC;
                vA = *(const float4*)(base + ((size_t)(iy0 * WW + ix0)) * CC + c0);
                vB = *(const float4*)(base + ((size_t)(iy1 * WW + ix0)) * CC + c0);
                vC = *(const float4*)(base + ((size_t)(iy0 * WW + ix1)) * CC + c0);
                vD = *(const float4*)(base + ((size_t)(iy1 * WW + ix1)) * CC + c0);
            } else {
                const float* base = fm + ((size_t)b * CC + c0) * HH * WW;
                int oA = iy0 * WW + ix0, oB = iy1 * WW + ix0;
                int oC = iy0 * WW + ix1, oD = iy1 * WW + ix1;
                vA.x = base[oA];           vB.x = base[oB];
                vC.x = base[oC];           vD.x = base[oD];
                vA.y = base[HH*WW + oA];   vB.y = base[HH*WW + oB];
                vC.y = base[HH*WW + oC];   vD.y = base[HH*WW + oD];
                vA.z = base[2*HH*WW + oA]; vB.z = base[2*HH*WW + oB];
                vC.z = base[2*HH*WW + oC]; vD.z = base[2*HH*WW + oD];
                vA.w = base[3*HH*WW + oA]; vB.w = base[3*HH*WW + oB];
                vC.w = base[3*HH*WW + oC]; vD.w = base[3*HH*WW + oD];
            }
            float4 v;
            v.x = wA * vA.x + wB * vB.x + wC * vC.x + wD * vD.x;
            v.y = wA * vA.y + wB * vB.y + wC * vC.y + wD * vD.y;
            v.z = wA * vA.z + wB * vB.z + wC * vC.z + wD * vD.z;
            v.w = wA * vA.w + wB * vB.w + wC * vC.w + wD * vD.w;
            acc.x = fmaxf(acc.x, v.x); acc.y = fmaxf(acc.y, v.y);
            acc.z = fmaxf(acc.z, v.z); acc.w = fmaxf(acc.w, v.w);
        }
        *(float4*)(&xs[k][c0]) = acc;
    }
    __syncthreads();
    for (int e = tid; e < 1024; e += 256) {
        int k = e >> 7, c = e & 127;
        ybn[k][c] = fmaxf(xs[k][c] * (bn1_g[c] * inv_s) + bn1_b[c], 0.0f);
    }
    __syncthreads();
    if (tid < 64) { z1[tid][0] = 0.0f; z1[tid][9] = 0.0f; }
    {
        int p = tid >> 2, kq = tid & 3;
        const float* wrow = w1 + p * 128;
        float a0a = 0.f, a0b = 0.f, a1a = 0.f, a1b = 0.f;
        #pragma unroll 8
        for (int c = 0; c < 128; c += 4) {
            float4 w  = *(const float4*)(wrow + c);
            float4 ya = *(const float4*)(&ybn[kq][c]);
            float4 yb = *(const float4*)(&ybn[kq + 4][c]);
            a0a = fmaf(w.x, ya.x, a0a); a0b = fmaf(w.y, ya.y, a0b);
            a0a = fmaf(w.z, ya.z, a0a); a0b = fmaf(w.w, ya.w, a0b);
            a1a = fmaf(w.x, yb.x, a1a); a1b = fmaf(w.y, yb.y, a1b);
            a1a = fmaf(w.z, yb.z, a1a); a1b = fmaf(w.w, yb.w, a1b);
        }
        float s2 = bn2_g[p] * inv_s, bb = bn2_b[p], cb = b1[p];
        z1[p][1 + kq]     = fmaxf((a0a + a0b + cb) * s2 + bb, 0.0f);
        z1[p][1 + kq + 4] = fmaxf((a1a + a1b + cb) * s2 + bb, 0.0f);
    }
    __syncthreads();
    {
        int p = tid >> 2, kq = tid & 3;
        const float* wrow = w2 + p * 192;
        float acc0 = 0.f, acc1 = 0.f;
        #pragma unroll 4
        for (int q = 0; q < 64; ++q) {
            float w0 = wrow[q * 3 + 0], w1v = wrow[q * 3 + 1], w2v = wrow[q * 3 + 2];
            const float* zr = &z1[q][0];
            acc0 = fmaf(w0, zr[kq], acc0);
            acc0 = fmaf(w1v, zr[kq + 1], acc0);
            acc0 = fmaf(w2v, zr[kq + 2], acc0);
            acc1 = fmaf(w0, zr[kq + 4], acc1);
            acc1 = fmaf(w1v, zr[kq + 5], acc1);
            acc1 = fmaf(w2v, zr[kq + 6], acc1);
        }
        float s3 = bn3_g[p] * inv_s, bb = bn3_b[p], cb = b2[p];
        z2[p][kq]     = fmaxf((acc0 + cb) * s3 + bb, 0.0f);
        z2[p][kq + 4] = fmaxf((acc1 + cb) * s3 + bb, 0.0f);
    }
    __syncthreads();
    float part0 = 0.f, part1 = 0.f, part2 = 0.f, part3 = 0.f;
    {
        int c = tid >> 1, kq = tid & 1;
        const float* wrow = w3 + c * 64;
        float acc[4] = {0.f, 0.f, 0.f, 0.f};
        #pragma unroll 8
        for (int q = 0; q < 64; ++q) {
            float w = wrow[q];
            acc[0] = fmaf(w, z2[q][kq], acc[0]);
            acc[1] = fmaf(w, z2[q][kq + 2], acc[1]);
            acc[2] = fmaf(w, z2[q][kq + 4], acc[2]);
            acc[3] = fmaf(w, z2[q][kq + 6], acc[3]);
        }
        float cb = b3[c];
        #pragma unroll
        for (int i = 0; i < 4; ++i) {
            int k = kq + 2 * i;
            float v = fmaxf(xs[k][c] + acc[i] + cb, 0.0f);
            int idx = c * 8 + k;
            part0 = fmaf(v, fcw[0 * FCK + idx], part0);
            part1 = fmaf(v, fcw[1 * FCK + idx], part1);
            part2 = fmaf(v, fcw[2 * FCK + idx], part2);
            part3 = fmaf(v, fcw[3 * FCK + idx], part3);
        }
    }
    #pragma unroll
    for (int off = 32; off > 0; off >>= 1) {
        part0 += __shfl_down(part0, off);
        part1 += __shfl_down(part1, off);
        part2 += __shfl_down(part2, off);
        part3 += __shfl_down(part3, off);
    }
    if ((tid & 63) == 0) {
        int w = tid >> 6;
        s_red[w * 4 + 0] = part0; s_red[w * 4 + 1] = part1;
        s_red[w * 4 + 2] = part2; s_red[w * 4 + 3] = part3;
    }
    __syncthreads();
    if (tid == 0) {
        float lg[4];
        #pragma unroll
        for (int o = 0; o < 4; ++o)
            lg[o] = fcb[o] + s_red[o] + s_red[4 + o] + s_red[8 + o] + s_red[12 + o];
        #pragma unroll
        for (int j = 0; j < FDIM; ++j) {
            float fv = fmaxf(s_feat[j], 0.0f);
            #pragma unroll
            for (int o = 0; o < 4; ++o)
                lg[o] = fmaf(fv, fcw[o * FCK + 1024 + j], lg[o]);
        }
        float m = fmaxf(fmaxf(lg[0], lg[1]), fmaxf(lg[2], lg[3]));
        float e0 = expf(lg[0] - m), e1 = expf(lg[1] - m);
        float e2 = expf(lg[2] - m), e3 = expf(lg[3] - m);
        float inv = 1.0f / (e0 + e1 + e2 + e3);
        float* lo = out + (size_t)L * 4;
        lo[0] = lg[0]; lo[1] = lg[1]; lo[2] = lg[2]; lo[3] = lg[3];
        float* pr = out + (size_t)BB * NLL * 4 + (size_t)L * 4;
        pr[0] = e0 * inv; pr[1] = e1 * inv; pr[2] = e2 * inv; pr[3] = e3 * inv;
    }
}

extern "C" void kernel_launch(void* const* d_in, const int* in_sizes, int n_in,
                              void* d_out, int out_size, void* d_ws, size_t ws_size,
                              hipStream_t stream) {
    const float* fm     = (const float*)d_in[0];
    const float* lines  = (const float*)d_in[1];
    const float* bn1_g  = (const float*)d_in[2];
    const float* bn1_b  = (const float*)d_in[3];
    const float* w1     = (const float*)d_in[4];
    const float* b1     = (const float*)d_in[5];
    const float* bn2_g  = (const float*)d_in[6];
    const float* bn2_b  = (const float*)d_in[7];
    const float* w2     = (const float*)d_in[8];
    const float* b2     = (const float*)d_in[9];
    const float* bn3_g  = (const float*)d_in[10];
    const float* bn3_b  = (const float*)d_in[11];
    const float* w3     = (const float*)d_in[12];
    const float* b3     = (const float*)d_in[13];
    const float* fcw    = (const float*)d_in[14];
    const float* fcb    = (const float*)d_in[15];
    float* out = (float*)d_out;

    const size_t fmTb_bytes = (size_t)BB * HH * WW * CC * sizeof(unsigned short); // 16 MiB
    const size_t fmTf_bytes = (size_t)BB * HH * WW * CC * sizeof(float);          // 32 MiB
    const size_t wb_bytes   = 57344;                    // W1b+W2b+W3b (bf16)
    const size_t fcwP_bytes = 4 * FCKP * sizeof(float); // 16512

    if (ws_size >= fmTb_bytes + wb_bytes + fcwP_bytes) {
        unsigned short* fmT = (unsigned short*)d_ws;
        unsigned short* W1b = (unsigned short*)((char*)d_ws + fmTb_bytes);
        unsigned short* W2b = W1b + 8192;
        unsigned short* W3b = W2b + 12288;
        float* fcwP = (float*)((char*)d_ws + fmTb_bytes + wb_bytes);
        transpose_prep<<<2048 + 16, 256, 0, stream>>>(
            fm, w1, w2, w3, fcw, fmT, W1b, W2b, W3b, fcwP);
        line_mfma<<<BB * NLL / 2, 256, 0, stream>>>(
            fmT, lines, bn1_g, bn1_b, W1b, b1, bn2_g, bn2_b, W2b, b2,
            bn3_g, bn3_b, W3b, b3, fcwP, fcb, out);
    } else if (ws_size >= fmTf_bytes) {
        float* fmT = (float*)d_ws;
        dim3 tg(CC / 32, BB * HH);
        transpose_fm2<<<tg, 256, 0, stream>>>(fm, fmT);
        line_kernel_v1<true><<<BB * NLL, 256, 0, stream>>>(
            fmT, lines, bn1_g, bn1_b, w1, b1, bn2_g, bn2_b, w2, b2,
            bn3_g, bn3_b, w3, b3, fcw, fcb, out);
    } else {
        line_kernel_v1<false><<<BB * NLL, 256, 0, stream>>>(
            fm, lines, bn1_g, bn1_b, w1, b1, bn2_g, bn2_b, w2, b2,
            bn3_g, bn3_b, w3, b3, fcw, fcb, out);
    }
}

// Round 11
// 148.949 us; speedup vs baseline: 1.1429x; 1.1429x over previous
//
#include <hip/hip_runtime.h>
#include <math.h>

#define BB 4
#define NLL 2048
#define CC 128
#define HH 128
#define WW 128
#define NPTS0 32
#define NPTS1 8
#define PP 64
#define FDIM 5
#define FCK (CC*NPTS1 + FDIM)   // 1029
#define FCKP 1032               // padded stride for aligned float4 loads

typedef __attribute__((ext_vector_type(8))) short bf16x8;
typedef __attribute__((ext_vector_type(4))) float f32x4;
typedef __attribute__((ext_vector_type(2))) float f32x2;
typedef __attribute__((ext_vector_type(4))) unsigned u32x4;

__device__ __forceinline__ unsigned short f2bf(float f) {
    union { float f; unsigned u; } v; v.f = f;
    unsigned u = v.u;
    return (unsigned short)((u + 0x7fffu + ((u >> 16) & 1u)) >> 16);
}
__device__ __forceinline__ float bf2f(unsigned short s) {
    union { unsigned u; float f; } v; v.u = ((unsigned)s) << 16;
    return v.f;
}
// HW bf16 pack: dst = {lo16=cvt(a), hi16=cvt(b)}, RNE — identical rounding to
// f2bf but 1 inst per 2 elements instead of ~8.
__device__ __forceinline__ unsigned cvt_pk_bf16(float a, float b) {
    unsigned r;
    asm("v_cvt_pk_bf16_f32 %0, %1, %2" : "=v"(r) : "v"(a), "v"(b));
    return r;
}
// Packed fp32 math (VOP3P): 2 lanes per instruction.
__device__ __forceinline__ f32x2 pk_mul(f32x2 a, f32x2 b) {
    f32x2 d;
    asm("v_pk_mul_f32 %0, %1, %2" : "=v"(d) : "v"(a), "v"(b));
    return d;
}
__device__ __forceinline__ f32x2 pk_fma(f32x2 a, f32x2 b, f32x2 c) {
    f32x2 d;
    asm("v_pk_fma_f32 %0, %1, %2, %3" : "=v"(d) : "v"(a), "v"(b), "v"(c));
    return d;
}
// u32 holding 2 packed bf16 -> f32x2 (2 VALU: shl for lo, and-mask for hi).
__device__ __forceinline__ f32x2 bfpair(unsigned u) {
    union { unsigned v; float f; } lo, hi;
    lo.v = u << 16;
    hi.v = u & 0xffff0000u;
    f32x2 r; r.x = lo.f; r.y = hi.f;
    return r;
}

// ---------------------------------------------------------------------------
// Transpose v7 (best measured): 2048 tile blocks + cvt_pk conversion.
// Blocks [2048,2064): weight prep.
// ---------------------------------------------------------------------------
__global__ __launch_bounds__(256)
void transpose_prep(const float* __restrict__ fm, const float* __restrict__ w1,
                    const float* __restrict__ w2, const float* __restrict__ w3,
                    const float* __restrict__ fcw,
                    unsigned short* __restrict__ fmT,
                    unsigned short* __restrict__ W1b,
                    unsigned short* __restrict__ W2b,
                    unsigned short* __restrict__ W3b,
                    float* __restrict__ fcwP) {
    const int t = threadIdx.x;
    if (blockIdx.x >= 2048) {
        int gid = (blockIdx.x - 2048) * 256 + t;
        for (int e = gid; e < 32800; e += 4096) {
            if (e < 8192) {
                W1b[e] = f2bf(w1[e]);
            } else if (e < 20480) {
                int g = e - 8192;
                int tt = g >> 12, r = g & 4095;
                int p = r >> 6, q = r & 63;
                W2b[tt * 4096 + p * 64 + q] = f2bf(w2[p * 192 + q * 3 + tt]);
            } else if (e < 28672) {
                int g = e - 20480;
                W3b[g] = f2bf(w3[g]);
            } else {
                int g = e - 28672;              // 0..4127
                int o = g / FCKP, r = g - o * FCKP;
                fcwP[g] = (r < FCK) ? fcw[o * FCK + r] : 0.0f;
            }
        }
        return;
    }
    __shared__ unsigned short tile[64 * 72];    // 9 KiB
    const int bh = blockIdx.x;
    const int by = bh >> 2;               // b*H + y
    const int xh = (bh >> 1) & 1;         // x half
    const int ch = bh & 1;                // channel half
    const int b = by >> 7, y = by & 127;
    const float* src = fm + ((size_t)b * CC + ch * 64) * (HH * WW)
                     + (size_t)y * WW + xh * 64;
    const int x4 = (t & 15) * 4;          // 0..60 within the x half
    #pragma unroll
    for (int i = 0; i < 4; ++i) {
        int r = (t >> 4) + 16 * i;        // channel within group, 0..63
        float4 v = *(const float4*)&src[(size_t)r * (HH * WW) + x4];
        uint2 u;
        u.x = cvt_pk_bf16(v.x, v.y);
        u.y = cvt_pk_bf16(v.z, v.w);
        *(uint2*)&tile[r * 72 + (x4 ^ (r & 28))] = u;
    }
    __syncthreads();
    const int c4 = (t & 15) * 4;          // channel (within group) 0..60
    unsigned short* dst = fmT + ((size_t)by * WW + xh * 64) * CC + ch * 64;
    #pragma unroll
    for (int i = 0; i < 4; ++i) {
        int x = (t >> 4) + 16 * i;        // 0..63
        ushort4 u;
        u.x = tile[(c4 + 0) * 72 + (x ^ ((c4 + 0) & 28))];
        u.y = tile[(c4 + 1) * 72 + (x ^ ((c4 + 1) & 28))];
        u.z = tile[(c4 + 2) * 72 + (x ^ ((c4 + 2) & 28))];
        u.w = tile[(c4 + 3) * 72 + (x ^ ((c4 + 3) & 28))];
        *(ushort4*)&dst[(size_t)x * CC + c4] = u;
    }
}

// ---------------------------------------------------------------------------
// Fused line pipeline v10 (BEST MEASURED: line_mfma 48.5us, total 152.03us).
// Restored after v11/v12 both spilled (WRITE_SIZE 0.26->66MB): the prefetch
// experiments are structurally infeasible -- P1's 64-VGPR gather payload
// cannot coexist in registers with the conv phases' weight set at any
// occupancy-compatible VGPR cap. 2 lines/block, 256 thr, 5 barriers,
// XCD swizzle, packed VALU (pk_mul/pk_fma/cvt_pk), float4 param loads.
// Floor accounting: harness fills ~96us @70% HBM peak (uncontrollable) +
// transpose ~8us @BW roofline + line_mfma 48.5us (latency floor, invariant
// to occupancy 33-76%, FETCH 47->16MB, barriers 5->0, MLP, -20% VALU).
// MFMA 16x16x32 bf16 mapping: A[m=lane&15][k=quad*8+j], C/D col=lane&15,
// row=quad*4+reg.
// ---------------------------------------------------------------------------
__global__ __launch_bounds__(256, 5)
void line_mfma(const unsigned short* __restrict__ fmT,   // (B,H,W,C) bf16
               const float* __restrict__ lines,
               const float* __restrict__ bn1_g, const float* __restrict__ bn1_b,
               const unsigned short* __restrict__ W1b, const float* __restrict__ b1,
               const float* __restrict__ bn2_g, const float* __restrict__ bn2_b,
               const unsigned short* __restrict__ W2b, const float* __restrict__ b2,
               const float* __restrict__ bn3_g, const float* __restrict__ bn3_b,
               const unsigned short* __restrict__ W3b, const float* __restrict__ b3,
               const float* __restrict__ fcwP,  const float* __restrict__ fcb,
               float* __restrict__ out) {
    __shared__ int   s_oA[64], s_oB[64], s_oC[64], s_oD[64];   // element offsets
    __shared__ float s_wA[64], s_wB[64], s_wC[64], s_wD[64];
    __shared__ float s_xs[16 * 132];             // residual, fp32, [m][c] pad 4
    __shared__ unsigned short s_ybn[16 * 136];   // relu(bn1), bf16, [m][c]
    __shared__ unsigned short s_z1[2 * 10 * 72]; // conv1 out, halo rows 0/9 zero
    __shared__ unsigned short s_z2[16 * 72];     // conv2 out, [m][q]
    __shared__ float s_feat[2][8];
    __shared__ float s_red[4 * 8];

    const int bx  = blockIdx.x;
    const int wg  = (bx & 7) * 512 + (bx >> 3);  // XCD swizzle: 1 batch per 2 XCDs
    const int L0  = wg * 2;
    const int b   = wg >> 10;
    const int tid = threadIdx.x;
    const int lane = tid & 63;
    const int wv   = tid >> 6;
    const int quad = lane >> 4;
    const int l16  = lane & 15;
    const float inv_s = 1.0f / sqrtf(1.0f + 1e-5f);

    // ---- P0: per-point offsets/weights, line features, halo zeroing ----
    if (tid < 64) {
        int line = tid >> 5, pt = tid & 31;
        const float* ln = lines + (size_t)(L0 + line) * 4;
        float lam = (float)pt * (1.0f / 31.0f);
        float om  = 1.0f - lam;
        float px = ln[0] * lam + ln[2] * om - 0.5f;
        float py = ln[1] * lam + ln[3] * om - 0.5f;
        float px0 = fminf(fmaxf(floorf(px), 0.0f), 127.0f);
        float py0 = fminf(fmaxf(floorf(py), 0.0f), 127.0f);
        float px1 = fminf(px0 + 1.0f, 127.0f);
        float py1 = fminf(py0 + 1.0f, 127.0f);
        int ix0 = (int)px0, ix1 = (int)px1, iy0 = (int)py0, iy1 = (int)py1;
        s_oA[tid] = (iy0 * WW + ix0) * CC;
        s_oB[tid] = (iy1 * WW + ix0) * CC;
        s_oC[tid] = (iy0 * WW + ix1) * CC;
        s_oD[tid] = (iy1 * WW + ix1) * CC;
        float ax = px1 - px, bxv = px - px0, ay = py1 - py, byv = py - py0;
        // exact reference pairing (its bilinear weights are x/y-swapped)
        s_wA[tid] = ax  * ay;
        s_wB[tid] = bxv * ay;
        s_wC[tid] = ax  * byv;
        s_wD[tid] = bxv * byv;
    }
    if (tid >= 64 && tid < 66) {
        int line = tid - 64;
        const float* ln = lines + (size_t)(L0 + line) * 4;
        float ux = ln[0], uy = ln[1], vx = ln[2], vy = ln[3];
        float dx = ux - vx, dy = uy - vy;
        float d = fmaxf(sqrtf(dx * dx + dy * dy), 1e-6f);
        s_feat[line][0] = ux * (1.0f / 128.0f);
        s_feat[line][1] = uy * (1.0f / 128.0f);
        s_feat[line][2] = vx * (1.0f / 128.0f);
        s_feat[line][3] = vy * (1.0f / 128.0f);
        s_feat[line][4] = d;
    }
    if (tid < 128) {
        int line = tid >> 6, q = tid & 63;
        s_z1[line * 720 + 0 * 72 + q] = 0;
        s_z1[line * 720 + 9 * 72 + q] = 0;
    }
    __syncthreads();

    // ---- P1: bf16 gather + packed bilinear + maxpool(4) -> s_xs (fp32)
    //          + fused bn1+relu+cvt_pk -> s_ybn ----
    {
        int tl = tid >> 4;               // m = line*8 + k, 0..15
        int c8 = (tid & 15) * 8;
        const unsigned short* base = fmT + (size_t)b * (HH * WW * CC) + c8;
        const int pt0 = (tl >> 3) * 32 + (tl & 7) * 4;
        u32x4 rA[4], rB[4], rC[4], rD[4];
        #pragma unroll
        for (int j = 0; j < 4; ++j) {
            rA[j] = *(const u32x4*)(base + s_oA[pt0 + j]);
            rB[j] = *(const u32x4*)(base + s_oB[pt0 + j]);
            rC[j] = *(const u32x4*)(base + s_oC[pt0 + j]);
            rD[j] = *(const u32x4*)(base + s_oD[pt0 + j]);
        }
        float acc[8];
        #pragma unroll
        for (int i = 0; i < 8; ++i) acc[i] = -INFINITY;
        #pragma unroll
        for (int j = 0; j < 4; ++j) {
            int pt = pt0 + j;
            float wA = s_wA[pt], wB = s_wB[pt], wC = s_wC[pt], wD = s_wD[pt];
            f32x2 wA2 = {wA, wA}, wB2 = {wB, wB};
            f32x2 wC2 = {wC, wC}, wD2 = {wD, wD};
            #pragma unroll
            for (int p2 = 0; p2 < 4; ++p2) {
                f32x2 t = pk_mul(wA2, bfpair(rA[j][p2]));
                t = pk_fma(wB2, bfpair(rB[j][p2]), t);
                t = pk_fma(wC2, bfpair(rC[j][p2]), t);
                t = pk_fma(wD2, bfpair(rD[j][p2]), t);
                acc[2 * p2]     = fmaxf(acc[2 * p2],     t.x);
                acc[2 * p2 + 1] = fmaxf(acc[2 * p2 + 1], t.y);
            }
        }
        float* xr = &s_xs[tl * 132 + c8];
        f32x4 lo = {acc[0], acc[1], acc[2], acc[3]};
        f32x4 hi = {acc[4], acc[5], acc[6], acc[7]};
        *(f32x4*)&xr[0] = lo;
        *(f32x4*)&xr[4] = hi;
        // fused bn1 + relu + packed cvt (vectorized param loads)
        float4 g0 = *(const float4*)(bn1_g + c8);
        float4 g1 = *(const float4*)(bn1_g + c8 + 4);
        float4 v0 = *(const float4*)(bn1_b + c8);
        float4 v1 = *(const float4*)(bn1_b + c8 + 4);
        float y0 = fmaxf(acc[0] * (g0.x * inv_s) + v0.x, 0.0f);
        float y1 = fmaxf(acc[1] * (g0.y * inv_s) + v0.y, 0.0f);
        float y2 = fmaxf(acc[2] * (g0.z * inv_s) + v0.z, 0.0f);
        float y3 = fmaxf(acc[3] * (g0.w * inv_s) + v0.w, 0.0f);
        float y4 = fmaxf(acc[4] * (g1.x * inv_s) + v1.x, 0.0f);
        float y5 = fmaxf(acc[5] * (g1.y * inv_s) + v1.y, 0.0f);
        float y6 = fmaxf(acc[6] * (g1.z * inv_s) + v1.z, 0.0f);
        float y7 = fmaxf(acc[7] * (g1.w * inv_s) + v1.w, 0.0f);
        u32x4 pk;
        pk[0] = cvt_pk_bf16(y0, y1);
        pk[1] = cvt_pk_bf16(y2, y3);
        pk[2] = cvt_pk_bf16(y4, y5);
        pk[3] = cvt_pk_bf16(y6, y7);
        *(u32x4*)&s_ybn[tl * 136 + c8] = pk;
    }
    __syncthreads();

    // ---- P2: conv1 (M=16,K=128,N=64) + bn2 + relu -> s_z1 ----
    {
        int n0 = wv * 16;
        f32x4 acc = {0.f, 0.f, 0.f, 0.f};
        #pragma unroll
        for (int kc = 0; kc < 4; ++kc) {
            bf16x8 a = *(const bf16x8*)&s_ybn[l16 * 136 + kc * 32 + quad * 8];
            bf16x8 bf = *(const bf16x8*)(W1b + (n0 + l16) * 128 + kc * 32 + quad * 8);
            acc = __builtin_amdgcn_mfma_f32_16x16x32_bf16(a, bf, acc, 0, 0, 0);
        }
        int p = n0 + l16;
        float s2 = bn2_g[p] * inv_s, bb2 = bn2_b[p], cb = b1[p];
        int line = quad >> 1;
        int kbase = (quad & 1) * 4;
        float v0 = fmaxf((acc[0] + cb) * s2 + bb2, 0.0f);
        float v1 = fmaxf((acc[1] + cb) * s2 + bb2, 0.0f);
        float v2 = fmaxf((acc[2] + cb) * s2 + bb2, 0.0f);
        float v3 = fmaxf((acc[3] + cb) * s2 + bb2, 0.0f);
        unsigned pk01 = cvt_pk_bf16(v0, v1);
        unsigned pk23 = cvt_pk_bf16(v2, v3);
        unsigned short* zr = &s_z1[line * 720 + (kbase + 1) * 72 + p];
        zr[0 * 72] = (unsigned short)pk01;
        zr[1 * 72] = (unsigned short)(pk01 >> 16);
        zr[2 * 72] = (unsigned short)pk23;
        zr[3 * 72] = (unsigned short)(pk23 >> 16);
    }
    __syncthreads();

    // ---- P3: conv2 (3 shifted GEMMs, M=16,K=64,N=64) + bn3 + relu -> s_z2 ----
    {
        int n0 = wv * 16;
        f32x4 acc = {0.f, 0.f, 0.f, 0.f};
        int line = l16 >> 3, k = l16 & 7;
        #pragma unroll
        for (int t = 0; t < 3; ++t) {
            const unsigned short* arow = &s_z1[line * 720 + (k + t) * 72];
            #pragma unroll
            for (int kc = 0; kc < 2; ++kc) {
                bf16x8 a = *(const bf16x8*)&arow[kc * 32 + quad * 8];
                bf16x8 bf = *(const bf16x8*)(W2b + t * 4096 + (n0 + l16) * 64 + kc * 32 + quad * 8);
                acc = __builtin_amdgcn_mfma_f32_16x16x32_bf16(a, bf, acc, 0, 0, 0);
            }
        }
        int p = n0 + l16;
        float s3 = bn3_g[p] * inv_s, bb3 = bn3_b[p], cb = b2[p];
        float v0 = fmaxf((acc[0] + cb) * s3 + bb3, 0.0f);
        float v1 = fmaxf((acc[1] + cb) * s3 + bb3, 0.0f);
        float v2 = fmaxf((acc[2] + cb) * s3 + bb3, 0.0f);
        float v3 = fmaxf((acc[3] + cb) * s3 + bb3, 0.0f);
        unsigned pk01 = cvt_pk_bf16(v0, v1);
        unsigned pk23 = cvt_pk_bf16(v2, v3);
        unsigned short* zr = &s_z2[(quad * 4) * 72 + p];
        zr[0 * 72] = (unsigned short)pk01;
        zr[1 * 72] = (unsigned short)(pk01 >> 16);
        zr[2 * 72] = (unsigned short)pk23;
        zr[3 * 72] = (unsigned short)(pk23 >> 16);
    }
    __syncthreads();

    // ---- P4: conv3 (M=16,K=64,N=128) + residual + relu + fc2 partials ----
    f32x2 P0 = {0.f, 0.f}, P1v = {0.f, 0.f}, P2v = {0.f, 0.f}, P3v = {0.f, 0.f};
    {
        int kbase = (quad & 1) * 4;
        bf16x8 a0 = *(const bf16x8*)&s_z2[l16 * 72 + 0 * 32 + quad * 8];
        bf16x8 a1 = *(const bf16x8*)&s_z2[l16 * 72 + 1 * 32 + quad * 8];
        #pragma unroll
        for (int sub = 0; sub < 2; ++sub) {
            int n0 = wv * 32 + sub * 16;
            f32x4 acc = {0.f, 0.f, 0.f, 0.f};
            bf16x8 bf0 = *(const bf16x8*)(W3b + (n0 + l16) * 64 + 0 * 32 + quad * 8);
            bf16x8 bf1 = *(const bf16x8*)(W3b + (n0 + l16) * 64 + 1 * 32 + quad * 8);
            acc = __builtin_amdgcn_mfma_f32_16x16x32_bf16(a0, bf0, acc, 0, 0, 0);
            acc = __builtin_amdgcn_mfma_f32_16x16x32_bf16(a1, bf1, acc, 0, 0, 0);
            int c = n0 + l16;
            float cb = b3[c];
            int idx = c * 8 + kbase;
            float4 w0 = *(const float4*)(fcwP + 0 * FCKP + idx);
            float4 w1w = *(const float4*)(fcwP + 1 * FCKP + idx);
            float4 w2w = *(const float4*)(fcwP + 2 * FCKP + idx);
            float4 w3w = *(const float4*)(fcwP + 3 * FCKP + idx);
            #pragma unroll
            for (int rp = 0; rp < 2; ++rp) {
                int m = quad * 4 + rp * 2;
                float e0 = fmaxf(s_xs[m * 132 + c] + acc[rp * 2] + cb, 0.0f);
                float e1 = fmaxf(s_xs[(m + 1) * 132 + c] + acc[rp * 2 + 1] + cb, 0.0f);
                f32x2 vv = {e0, e1};
                float w0lo = rp ? w0.z : w0.x,  w0hi = rp ? w0.w : w0.y;
                float w1lo = rp ? w1w.z : w1w.x, w1hi = rp ? w1w.w : w1w.y;
                float w2lo = rp ? w2w.z : w2w.x, w2hi = rp ? w2w.w : w2w.y;
                float w3lo = rp ? w3w.z : w3w.x, w3hi = rp ? w3w.w : w3w.y;
                f32x2 w0p = {w0lo, w0hi}, w1p = {w1lo, w1hi};
                f32x2 w2p = {w2lo, w2hi}, w3p = {w3lo, w3hi};
                P0  = pk_fma(vv, w0p, P0);
                P1v = pk_fma(vv, w1p, P1v);
                P2v = pk_fma(vv, w2p, P2v);
                P3v = pk_fma(vv, w3p, P3v);
            }
        }
    }
    float p0 = P0.x + P0.y, p1 = P1v.x + P1v.y;
    float p2 = P2v.x + P2v.y, p3 = P3v.x + P3v.y;
    #pragma unroll
    for (int off = 16; off >= 1; off >>= 1) {
        p0 += __shfl_down(p0, off);
        p1 += __shfl_down(p1, off);
        p2 += __shfl_down(p2, off);
        p3 += __shfl_down(p3, off);
    }
    if ((lane & 31) == 0) {
        int line = lane >> 5;
        s_red[wv * 8 + line * 4 + 0] = p0;
        s_red[wv * 8 + line * 4 + 1] = p1;
        s_red[wv * 8 + line * 4 + 2] = p2;
        s_red[wv * 8 + line * 4 + 3] = p3;
    }
    __syncthreads();

    // ---- P5: finish logits + softmax ----
    if (tid < 2) {
        int line = tid;
        float lg[4];
        #pragma unroll
        for (int o = 0; o < 4; ++o) {
            lg[o] = fcb[o] + s_red[0 + line * 4 + o] + s_red[8 + line * 4 + o]
                  + s_red[16 + line * 4 + o] + s_red[24 + line * 4 + o];
        }
        #pragma unroll
        for (int j = 0; j < FDIM; ++j) {
            float fv = fmaxf(s_feat[line][j], 0.0f);
            #pragma unroll
            for (int o = 0; o < 4; ++o)
                lg[o] = fmaf(fv, fcwP[o * FCKP + 1024 + j], lg[o]);
        }
        float m = fmaxf(fmaxf(lg[0], lg[1]), fmaxf(lg[2], lg[3]));
        float e0 = expf(lg[0] - m), e1 = expf(lg[1] - m);
        float e2 = expf(lg[2] - m), e3 = expf(lg[3] - m);
        float inv = 1.0f / (e0 + e1 + e2 + e3);
        float* lo = out + (size_t)(L0 + line) * 4;
        lo[0] = lg[0]; lo[1] = lg[1]; lo[2] = lg[2]; lo[3] = lg[3];
        float* pr = out + (size_t)BB * NLL * 4 + (size_t)(L0 + line) * 4;
        pr[0] = e0 * inv; pr[1] = e1 * inv; pr[2] = e2 * inv; pr[3] = e3 * inv;
    }
}

// ---------------------------------------------------------------------------
// Fallbacks (small-ws paths): round-1 proven VALU kernel + fp32 transpose.
// ---------------------------------------------------------------------------
__global__ __launch_bounds__(256)
void transpose_fm2(const float* __restrict__ fm, float* __restrict__ fmT) {
    __shared__ float tile[32 * 132];
    const int c0 = blockIdx.x * 32;
    const int by = blockIdx.y;
    const int b = by >> 7, y = by & 127;
    const int t = threadIdx.x;
    const float* src = fm + ((size_t)b * CC) * (HH * WW) + (size_t)y * WW;
    const int x4 = (t & 31) * 4;
    #pragma unroll
    for (int i = 0; i < 4; ++i) {
        int r = (t >> 5) + 8 * i;
        *(float4*)&tile[r * 132 + x4] =
            *(const float4*)&src[(size_t)(c0 + r) * (HH * WW) + x4];
    }
    __syncthreads();
    float* dst = fmT + (size_t)by * WW * CC + c0 + (t & 31);
    const int cr = (t & 31) * 132;
    #pragma unroll
    for (int i = 0; i < 16; ++i) {
        int x = (t >> 5) + 8 * i;
        dst[(size_t)x * CC] = tile[cr + x];
    }
}

template<bool TRANS>
__global__ __launch_bounds__(256)
void line_kernel_v1(const float* __restrict__ fm,
                    const float* __restrict__ lines,
                    const float* __restrict__ bn1_g, const float* __restrict__ bn1_b,
                    const float* __restrict__ w1,    const float* __restrict__ b1,
                    const float* __restrict__ bn2_g, const float* __restrict__ bn2_b,
                    const float* __restrict__ w2,    const float* __restrict__ b2,
                    const float* __restrict__ bn3_g, const float* __restrict__ bn3_b,
                    const float* __restrict__ w3,    const float* __restrict__ b3,
                    const float* __restrict__ fcw,   const float* __restrict__ fcb,
                    float* __restrict__ out) {
    __shared__ int   s_ix0[32], s_ix1[32], s_iy0[32], s_iy1[32];
    __shared__ float s_wA[32], s_wB[32], s_wC[32], s_wD[32];
    __shared__ float xs [8][132];
    __shared__ float ybn[8][132];
    __shared__ float z1 [64][12];
    __shared__ float z2 [64][8];
    __shared__ float s_feat[8];
    __shared__ float s_red[16];

    const int L   = blockIdx.x;
    const int b   = L / NLL;
    const int tid = threadIdx.x;
    const float inv_s = 1.0f / sqrtf(1.0f + 1e-5f);
    const float* ln = lines + (size_t)L * 4;

    if (tid < 32) {
        float lam = (float)tid * (1.0f / 31.0f);
        float om  = 1.0f - lam;
        float px = ln[0] * lam + ln[2] * om - 0.5f;
        float py = ln[1] * lam + ln[3] * om - 0.5f;
        float px0 = fminf(fmaxf(floorf(px), 0.0f), 127.0f);
        float py0 = fminf(fmaxf(floorf(py), 0.0f), 127.0f);
        float px1 = fminf(px0 + 1.0f, 127.0f);
        float py1 = fminf(py0 + 1.0f, 127.0f);
        s_ix0[tid] = (int)px0; s_ix1[tid] = (int)px1;
        s_iy0[tid] = (int)py0; s_iy1[tid] = (int)py1;
        float ax = px1 - px, bxv = px - px0, ay = py1 - py, byv = py - py0;
        s_wA[tid] = ax  * ay;  s_wB[tid] = bxv * ay;
        s_wC[tid] = ax  * byv; s_wD[tid] = bxv * byv;
    }
    if (tid == 0) {
        float ux = ln[0], uy = ln[1], vx = ln[2], vy = ln[3];
        float dx = ux - vx, dy = uy - vy;
        float d = fmaxf(sqrtf(dx * dx + dy * dy), 1e-6f);
        s_feat[0] = ux / 128.0f; s_feat[1] = uy / 128.0f;
        s_feat[2] = vx / 128.0f; s_feat[3] = vy / 128.0f;
        s_feat[4] = d;
    }
    __syncthreads();
    {
        int cq = tid & 31, k = tid >> 5, c0 = cq * 4;
        float4 acc;
        acc.x = -INFINITY; acc.y = -INFINITY; acc.z = -INFINITY; acc.w = -INFINITY;
        #pragma unroll
        for (int j = 0; j < 4; ++j) {
            int pt = k * 4 + j;
            int ix0 = s_ix0[pt], ix1 = s_ix1[pt];
            int iy0 = s_iy0[pt], iy1 = s_iy1[pt];
            float wA = s_wA[pt], wB = s_wB[pt], wC = s_wC[pt], wD = s_wD[pt];
            float4 vA, vB, vC, vD;
            if (TRANS) {
                const float* base = fm + (size_t)b * HH * WW * CC;
                vA = *(const float4*)(base + ((size_t)(iy0 * WW + ix0)) * CC + c0);
                vB = *(const float4*)(base + ((size_t)(iy1 * WW + ix0)) * CC + c0);
                vC = *(const float4*)(base + ((size_t)(iy0 * WW + ix1)) * CC + c0);
                vD = *(const float4*)(base + ((size_t)(iy1 * WW + ix1)) * CC + c0);
            } else {
                const float* base = fm + ((size_t)b * CC + c0) * HH * WW;
                int oA = iy0 * WW + ix0, oB = iy1 * WW + ix0;
                int oC = iy0 * WW + ix1, oD = iy1 * WW + ix1;
                vA.x = base[oA];           vB.x = base[oB];
                vC.x = base[oC];           vD.x = base[oD];
                vA.y = base[HH*WW + oA];   vB.y = base[HH*WW + oB];
                vC.y = base[HH*WW + oC];   vD.y = base[HH*WW + oD];
                vA.z = base[2*HH*WW + oA]; vB.z = base[2*HH*WW + oB];
                vC.z = base[2*HH*WW + oC]; vD.z = base[2*HH*WW + oD];
                vA.w = base[3*HH*WW + oA]; vB.w = base[3*HH*WW + oB];
                vC.w = base[3*HH*WW + oC]; vD.w = base[3*HH*WW + oD];
            }
            float4 v;
            v.x = wA * vA.x + wB * vB.x + wC * vC.x + wD * vD.x;
            v.y = wA * vA.y + wB * vB.y + wC * vC.y + wD * vD.y;
            v.z = wA * vA.z + wB * vB.z + wC * vC.z + wD * vD.z;
            v.w = wA * vA.w + wB * vB.w + wC * vC.w + wD * vD.w;
            acc.x = fmaxf(acc.x, v.x); acc.y = fmaxf(acc.y, v.y);
            acc.z = fmaxf(acc.z, v.z); acc.w = fmaxf(acc.w, v.w);
        }
        *(float4*)(&xs[k][c0]) = acc;
    }
    __syncthreads();
    for (int e = tid; e < 1024; e += 256) {
        int k = e >> 7, c = e & 127;
        ybn[k][c] = fmaxf(xs[k][c] * (bn1_g[c] * inv_s) + bn1_b[c], 0.0f);
    }
    __syncthreads();
    if (tid < 64) { z1[tid][0] = 0.0f; z1[tid][9] = 0.0f; }
    {
        int p = tid >> 2, kq = tid & 3;
        const float* wrow = w1 + p * 128;
        float a0a = 0.f, a0b = 0.f, a1a = 0.f, a1b = 0.f;
        #pragma unroll 8
        for (int c = 0; c < 128; c += 4) {
            float4 w  = *(const float4*)(wrow + c);
            float4 ya = *(const float4*)(&ybn[kq][c]);
            float4 yb = *(const float4*)(&ybn[kq + 4][c]);
            a0a = fmaf(w.x, ya.x, a0a); a0b = fmaf(w.y, ya.y, a0b);
            a0a = fmaf(w.z, ya.z, a0a); a0b = fmaf(w.w, ya.w, a0b);
            a1a = fmaf(w.x, yb.x, a1a); a1b = fmaf(w.y, yb.y, a1b);
            a1a = fmaf(w.z, yb.z, a1a); a1b = fmaf(w.w, yb.w, a1b);
        }
        float s2 = bn2_g[p] * inv_s, bb = bn2_b[p], cb = b1[p];
        z1[p][1 + kq]     = fmaxf((a0a + a0b + cb) * s2 + bb, 0.0f);
        z1[p][1 + kq + 4] = fmaxf((a1a + a1b + cb) * s2 + bb, 0.0f);
    }
    __syncthreads();
    {
        int p = tid >> 2, kq = tid & 3;
        const float* wrow = w2 + p * 192;
        float acc0 = 0.f, acc1 = 0.f;
        #pragma unroll 4
        for (int q = 0; q < 64; ++q) {
            float w0 = wrow[q * 3 + 0], w1v = wrow[q * 3 + 1], w2v = wrow[q * 3 + 2];
            const float* zr = &z1[q][0];
            acc0 = fmaf(w0, zr[kq], acc0);
            acc0 = fmaf(w1v, zr[kq + 1], acc0);
            acc0 = fmaf(w2v, zr[kq + 2], acc0);
            acc1 = fmaf(w0, zr[kq + 4], acc1);
            acc1 = fmaf(w1v, zr[kq + 5], acc1);
            acc1 = fmaf(w2v, zr[kq + 6], acc1);
        }
        float s3 = bn3_g[p] * inv_s, bb = bn3_b[p], cb = b2[p];
        z2[p][kq]     = fmaxf((acc0 + cb) * s3 + bb, 0.0f);
        z2[p][kq + 4] = fmaxf((acc1 + cb) * s3 + bb, 0.0f);
    }
    __syncthreads();
    float part0 = 0.f, part1 = 0.f, part2 = 0.f, part3 = 0.f;
    {
        int c = tid >> 1, kq = tid & 1;
        const float* wrow = w3 + c * 64;
        float acc[4] = {0.f, 0.f, 0.f, 0.f};
        #pragma unroll 8
        for (int q = 0; q < 64; ++q) {
            float w = wrow[q];
            acc[0] = fmaf(w, z2[q][kq], acc[0]);
            acc[1] = fmaf(w, z2[q][kq + 2], acc[1]);
            acc[2] = fmaf(w, z2[q][kq + 4], acc[2]);
            acc[3] = fmaf(w, z2[q][kq + 6], acc[3]);
        }
        float cb = b3[c];
        #pragma unroll
        for (int i = 0; i < 4; ++i) {
            int k = kq + 2 * i;
            float v = fmaxf(xs[k][c] + acc[i] + cb, 0.0f);
            int idx = c * 8 + k;
            part0 = fmaf(v, fcw[0 * FCK + idx], part0);
            part1 = fmaf(v, fcw[1 * FCK + idx], part1);
            part2 = fmaf(v, fcw[2 * FCK + idx], part2);
            part3 = fmaf(v, fcw[3 * FCK + idx], part3);
        }
    }
    #pragma unroll
    for (int off = 32; off > 0; off >>= 1) {
        part0 += __shfl_down(part0, off);
        part1 += __shfl_down(part1, off);
        part2 += __shfl_down(part2, off);
        part3 += __shfl_down(part3, off);
    }
    if ((tid & 63) == 0) {
        int w = tid >> 6;
        s_red[w * 4 + 0] = part0; s_red[w * 4 + 1] = part1;
        s_red[w * 4 + 2] = part2; s_red[w * 4 + 3] = part3;
    }
    __syncthreads();
    if (tid == 0) {
        float lg[4];
        #pragma unroll
        for (int o = 0; o < 4; ++o)
            lg[o] = fcb[o] + s_red[o] + s_red[4 + o] + s_red[8 + o] + s_red[12 + o];
        #pragma unroll
        for (int j = 0; j < FDIM; ++j) {
            float fv = fmaxf(s_feat[j], 0.0f);
            #pragma unroll
            for (int o = 0; o < 4; ++o)
                lg[o] = fmaf(fv, fcw[o * FCK + 1024 + j], lg[o]);
        }
        float m = fmaxf(fmaxf(lg[0], lg[1]), fmaxf(lg[2], lg[3]));
        float e0 = expf(lg[0] - m), e1 = expf(lg[1] - m);
        float e2 = expf(lg[2] - m), e3 = expf(lg[3] - m);
        float inv = 1.0f / (e0 + e1 + e2 + e3);
        float* lo = out + (size_t)L * 4;
        lo[0] = lg[0]; lo[1] = lg[1]; lo[2] = lg[2]; lo[3] = lg[3];
        float* pr = out + (size_t)BB * NLL * 4 + (size_t)L * 4;
        pr[0] = e0 * inv; pr[1] = e1 * inv; pr[2] = e2 * inv; pr[3] = e3 * inv;
    }
}

extern "C" void kernel_launch(void* const* d_in, const int* in_sizes, int n_in,
                              void* d_out, int out_size, void* d_ws, size_t ws_size,
                              hipStream_t stream) {
    const float* fm     = (const float*)d_in[0];
    const float* lines  = (const float*)d_in[1];
    const float* bn1_g  = (const float*)d_in[2];
    const float* bn1_b  = (const float*)d_in[3];
    const float* w1     = (const float*)d_in[4];
    const float* b1     = (const float*)d_in[5];
    const float* bn2_g  = (const float*)d_in[6];
    const float* bn2_b  = (const float*)d_in[7];
    const float* w2     = (const float*)d_in[8];
    const float* b2     = (const float*)d_in[9];
    const float* bn3_g  = (const float*)d_in[10];
    const float* bn3_b  = (const float*)d_in[11];
    const float* w3     = (const float*)d_in[12];
    const float* b3     = (const float*)d_in[13];
    const float* fcw    = (const float*)d_in[14];
    const float* fcb    = (const float*)d_in[15];
    float* out = (float*)d_out;

    const size_t fmTb_bytes = (size_t)BB * HH * WW * CC * sizeof(unsigned short); // 16 MiB
    const size_t fmTf_bytes = (size_t)BB * HH * WW * CC * sizeof(float);          // 32 MiB
    const size_t wb_bytes   = 57344;                    // W1b+W2b+W3b (bf16)
    const size_t fcwP_bytes = 4 * FCKP * sizeof(float); // 16512

    if (ws_size >= fmTb_bytes + wb_bytes + fcwP_bytes) {
        unsigned short* fmT = (unsigned short*)d_ws;
        unsigned short* W1b = (unsigned short*)((char*)d_ws + fmTb_bytes);
        unsigned short* W2b = W1b + 8192;
        unsigned short* W3b = W2b + 12288;
        float* fcwP = (float*)((char*)d_ws + fmTb_bytes + wb_bytes);
        transpose_prep<<<2048 + 16, 256, 0, stream>>>(
            fm, w1, w2, w3, fcw, fmT, W1b, W2b, W3b, fcwP);
        line_mfma<<<BB * NLL / 2, 256, 0, stream>>>(
            fmT, lines, bn1_g, bn1_b, W1b, b1, bn2_g, bn2_b, W2b, b2,
            bn3_g, bn3_b, W3b, b3, fcwP, fcb, out);
    } else if (ws_size >= fmTf_bytes) {
        float* fmT = (float*)d_ws;
        dim3 tg(CC / 32, BB * HH);
        transpose_fm2<<<tg, 256, 0, stream>>>(fm, fmT);
        line_kernel_v1<true><<<BB * NLL, 256, 0, stream>>>(
            fmT, lines, bn1_g, bn1_b, w1, b1, bn2_g, bn2_b, w2, b2,
            bn3_g, bn3_b, w3, b3, fcw, fcb, out);
    } else {
        line_kernel_v1<false><<<BB * NLL, 256, 0, stream>>>(
            fm, lines, bn1_g, bn1_b, w1, b1, bn2_g, bn2_b, w2, b2,
            bn3_g, bn3_b, w3, b3, fcw, fcb, out);
    }
}